// Round 1
// baseline (41.810 us; speedup 1.0000x reference)
//
#include <hip/hip_runtime.h>
#include <math.h>

constexpr int B = 16, H = 16, KVH = 4, D = 128;
constexpr int BLK = 16, MAXB = 256, MAX_NNZ = 64;
constexpr int GRP = H / KVH; // 4

__global__ __launch_bounds__(256) void sparse_attn_kernel(
    const float* __restrict__ q,            // (B,H,D)
    const float* __restrict__ k_cache,      // (NB,KVH,32,16,4)
    const float* __restrict__ v_cache,      // (NB,KVH,128,16)
    const int* __restrict__ block_tables,   // (B,MAXB)
    const int* __restrict__ context_lens,   // (B,)
    const int* __restrict__ layout_crow,    // (H,MAXB+1)
    const int* __restrict__ layout_col,     // (H,collen)
    int collen,
    float* __restrict__ out)                // (B,H,D)
{
    const int bh = blockIdx.x;
    const int b = bh / H;
    const int h = bh % H;
    const int hkv = h / GRP;
    const int tid = threadIdx.x;
    const int lane = tid & 63;
    const int wv = tid >> 6;   // 0..3

    const int q_pid = context_lens[b] - 1;
    const int pbid = q_pid / BLK;
    const int row_off = h * (MAXB + 1) + pbid;
    const int start = layout_crow[row_off];
    const int nnz = layout_crow[row_off + 1] - start;   // 1..64

    __shared__ float s_q[D];
    __shared__ float s_p[MAX_NNZ * BLK];   // scores then probabilities (1024 f32)
    __shared__ int   s_bt[MAX_NNZ];
    __shared__ int   s_col[MAX_NNZ];
    __shared__ float s_red[4];

    if (tid < D) s_q[tid] = q[(b * H + h) * D + tid];
    if (tid < MAX_NNZ) {
        int c = 0;
        if (tid < nnz) c = layout_col[h * collen + start + tid];
        s_col[tid] = c;
        s_bt[tid] = block_tables[b * MAXB + c];
    }
    __syncthreads();

    const float sm_scale = 0.08838834764831845f; // 1/sqrt(128)

    // ---- scores: wave wv owns j in [wv*16, wv*16+16); 4 j's x 16 tokens per pass
    const int jj = lane >> 4;   // 0..3
    const int n  = lane & 15;
    #pragma unroll
    for (int jl = 0; jl < 4; ++jl) {
        const int j = wv * 16 + jl * 4 + jj;
        float sc = -INFINITY;
        if (j < nnz) {
            const int pos = s_col[j] * BLK + n;
            if (pos <= q_pid) {
                const float4* kb = (const float4*)(k_cache + (size_t)(s_bt[j] * KVH + hkv) * (D * BLK));
                const float4* qv4 = (const float4*)s_q;
                float acc = 0.f;
                #pragma unroll
                for (int d1 = 0; d1 < 32; ++d1) {
                    const float4 kv = kb[d1 * 16 + n];
                    const float4 qv = qv4[d1];
                    acc += kv.x * qv.x + kv.y * qv.y + kv.z * qv.z + kv.w * qv.w;
                }
                sc = acc * sm_scale;
            }
        }
        s_p[j * BLK + n] = sc;
    }
    __syncthreads();

    // ---- softmax over 1024 entries; each thread owns 4 consecutive entries
    float4 sv = ((const float4*)s_p)[tid];
    float m = fmaxf(fmaxf(sv.x, sv.y), fmaxf(sv.z, sv.w));
    #pragma unroll
    for (int off = 1; off < 64; off <<= 1)
        m = fmaxf(m, __shfl_xor(m, off));
    if (lane == 0) s_red[wv] = m;
    __syncthreads();
    m = fmaxf(fmaxf(s_red[0], s_red[1]), fmaxf(s_red[2], s_red[3]));

    float4 pv;
    pv.x = __expf(sv.x - m);
    pv.y = __expf(sv.y - m);
    pv.z = __expf(sv.z - m);
    pv.w = __expf(sv.w - m);
    ((float4*)s_p)[tid] = pv;
    float s = pv.x + pv.y + pv.z + pv.w;
    #pragma unroll
    for (int off = 1; off < 64; off <<= 1)
        s += __shfl_xor(s, off);
    __syncthreads();           // everyone done reading s_red(max) + writing s_p
    if (lane == 0) s_red[wv] = s;
    __syncthreads();
    const float inv = 1.f / (s_red[0] + s_red[1] + s_red[2] + s_red[3]);

    // ---- PV: thread t owns d = t/2, tokens n0..n0+7 (n0 = (t&1)*8)
    // element offset within 8KB v-block = d*16 + n0 = tid*8  -> coalesced
    float acc = 0.f;
    for (int j = 0; j < nnz; ++j) {
        const float4* vb = (const float4*)(v_cache + (size_t)(s_bt[j] * KVH + hkv) * (D * BLK));
        const float4 v0 = vb[tid * 2];
        const float4 v1 = vb[tid * 2 + 1];
        const float4 p0 = ((const float4*)s_p)[j * 4 + (tid & 1) * 2];
        const float4 p1 = ((const float4*)s_p)[j * 4 + (tid & 1) * 2 + 1];
        acc += v0.x * p0.x + v0.y * p0.y + v0.z * p0.z + v0.w * p0.w
             + v1.x * p1.x + v1.y * p1.y + v1.z * p1.z + v1.w * p1.w;
    }
    acc += __shfl_xor(acc, 1);
    if ((tid & 1) == 0) out[(b * H + h) * D + (tid >> 1)] = acc * inv;
}

extern "C" void kernel_launch(void* const* d_in, const int* in_sizes, int n_in,
                              void* d_out, int out_size, void* d_ws, size_t ws_size,
                              hipStream_t stream) {
    const float* q            = (const float*)d_in[0];
    const float* k_cache      = (const float*)d_in[1];
    const float* v_cache      = (const float*)d_in[2];
    const int*   block_tables = (const int*)d_in[3];
    const int*   context_lens = (const int*)d_in[4];
    const int*   layout_crow  = (const int*)d_in[5];
    const int*   layout_col   = (const int*)d_in[6];
    const int    collen       = in_sizes[6] / H;
    float* out = (float*)d_out;

    sparse_attn_kernel<<<B * H, 256, 0, stream>>>(
        q, k_cache, v_cache, block_tables, context_lens,
        layout_crow, layout_col, collen, out);
}

// Round 2
// 30.598 us; speedup vs baseline: 1.3664x; 1.3664x over previous
//
#include <hip/hip_runtime.h>
#include <math.h>

constexpr int B = 16, H = 16, KVH = 4, D = 128;
constexpr int BLK = 16, MAXB = 256, MAX_NNZ = 64;
constexpr int GRP = H / KVH;   // 4
constexpr int NSPLIT = 4;
constexpr int JPS = MAX_NNZ / NSPLIT;  // 16 sparse blocks per split

// ws layout: per (bh, split): [D floats partial_out][m][s]  -> D+2 floats
constexpr int WSTRIDE = D + 2;

__global__ __launch_bounds__(256) void sparse_attn_split(
    const float* __restrict__ q,            // (B,H,D)
    const float* __restrict__ k_cache,      // (NB,KVH,32,16,4)
    const float* __restrict__ v_cache,      // (NB,KVH,128,16)
    const int* __restrict__ block_tables,   // (B,MAXB)
    const int* __restrict__ context_lens,   // (B,)
    const int* __restrict__ layout_crow,    // (H,MAXB+1)
    const int* __restrict__ layout_col,     // (H,collen)
    int collen,
    float* __restrict__ ws)
{
    const int bh = blockIdx.x >> 2;         // /NSPLIT
    const int split = blockIdx.x & (NSPLIT - 1);
    const int b = bh / H;
    const int h = bh % H;
    const int hkv = h / GRP;
    const int tid = threadIdx.x;
    const int lane = tid & 63;
    const int wv = tid >> 6;

    const int q_pid = context_lens[b] - 1;
    const int pbid = q_pid / BLK;
    const int row_off = h * (MAXB + 1) + pbid;
    const int start = layout_crow[row_off];
    const int nnz = layout_crow[row_off + 1] - start;
    const int j0 = split * JPS;
    const int jcnt = min(JPS, nnz - j0);    // may be <= 0 (empty split)

    __shared__ float s_q[D];
    __shared__ float s_p[JPS * BLK];        // 256 floats
    __shared__ int   s_bt[JPS];
    __shared__ int   s_col[JPS];
    __shared__ float s_red[4];

    if (tid < D) s_q[tid] = q[(b * H + h) * D + tid];
    if (tid < JPS) {
        int c = 0;
        if (tid < jcnt) c = layout_col[h * collen + start + j0 + tid];
        s_col[tid] = c;
        s_bt[tid] = block_tables[b * MAXB + c];
    }
    __syncthreads();

    const float sm_scale = 0.08838834764831845f; // 1/sqrt(128)

    // ---- scores: one (j,n) per thread; wave wv covers j in [wv*4, wv*4+4)
    const int j = tid >> 4;    // 0..15
    const int n = tid & 15;
    float sc = -INFINITY;
    if (j < jcnt) {
        const int pos = s_col[j] * BLK + n;
        if (pos <= q_pid) {
            const float4* kb = (const float4*)(k_cache + (size_t)(s_bt[j] * KVH + hkv) * (D * BLK));
            const float4* qv4 = (const float4*)s_q;
            float acc = 0.f;
            #pragma unroll
            for (int d1 = 0; d1 < 32; ++d1) {
                const float4 kv = kb[d1 * 16 + n];
                const float4 qv = qv4[d1];
                acc += kv.x * qv.x + kv.y * qv.y + kv.z * qv.z + kv.w * qv.w;
            }
            sc = acc * sm_scale;
        }
    }

    // ---- local softmax (this split only)
    float m = sc;
    #pragma unroll
    for (int off = 1; off < 64; off <<= 1)
        m = fmaxf(m, __shfl_xor(m, off));
    if (lane == 0) s_red[wv] = m;
    __syncthreads();
    m = fmaxf(fmaxf(s_red[0], s_red[1]), fmaxf(s_red[2], s_red[3]));

    const float p = (sc == -INFINITY) ? 0.f : __expf(sc - m);  // NaN-safe for empty split
    s_p[tid] = p;   // == s_p[j*BLK + n]
    float s = p;
    #pragma unroll
    for (int off = 1; off < 64; off <<= 1)
        s += __shfl_xor(s, off);
    __syncthreads();           // s_red max reads done; s_p writes visible
    if (lane == 0) s_red[wv] = s;
    __syncthreads();
    const float ssum = s_red[0] + s_red[1] + s_red[2] + s_red[3];

    // ---- partial PV: thread t owns d = t/2, tokens n0..n0+7 (n0 = (t&1)*8)
    float acc = 0.f;
    for (int jj = 0; jj < jcnt; ++jj) {
        const float4* vb = (const float4*)(v_cache + (size_t)(s_bt[jj] * KVH + hkv) * (D * BLK));
        const float4 v0 = vb[tid * 2];
        const float4 v1 = vb[tid * 2 + 1];
        const float4 p0 = ((const float4*)s_p)[jj * 4 + (tid & 1) * 2];
        const float4 p1 = ((const float4*)s_p)[jj * 4 + (tid & 1) * 2 + 1];
        acc += v0.x * p0.x + v0.y * p0.y + v0.z * p0.z + v0.w * p0.w
             + v1.x * p1.x + v1.y * p1.y + v1.z * p1.z + v1.w * p1.w;
    }
    acc += __shfl_xor(acc, 1);

    float* wsp = ws + (size_t)(bh * NSPLIT + split) * WSTRIDE;
    if ((tid & 1) == 0) wsp[tid >> 1] = acc;   // partial out (unnormalized, local max)
    if (tid == 0) { wsp[D] = m; wsp[D + 1] = ssum; }
}

__global__ __launch_bounds__(128) void sparse_attn_combine(
    const float* __restrict__ ws,
    float* __restrict__ out)
{
    const int bh = blockIdx.x;
    const int d = threadIdx.x;
    const float* base = ws + (size_t)bh * NSPLIT * WSTRIDE;

    float m = -INFINITY;
    #pragma unroll
    for (int sidx = 0; sidx < NSPLIT; ++sidx)
        m = fmaxf(m, base[sidx * WSTRIDE + D]);

    float num = 0.f, den = 0.f;
    #pragma unroll
    for (int sidx = 0; sidx < NSPLIT; ++sidx) {
        const float ms = base[sidx * WSTRIDE + D];
        const float ss = base[sidx * WSTRIDE + D + 1];
        const float a = (ms == -INFINITY) ? 0.f : __expf(ms - m);
        num += base[sidx * WSTRIDE + d] * a;
        den += ss * a;
    }
    out[bh * D + d] = num / den;
}

extern "C" void kernel_launch(void* const* d_in, const int* in_sizes, int n_in,
                              void* d_out, int out_size, void* d_ws, size_t ws_size,
                              hipStream_t stream) {
    const float* q            = (const float*)d_in[0];
    const float* k_cache      = (const float*)d_in[1];
    const float* v_cache      = (const float*)d_in[2];
    const int*   block_tables = (const int*)d_in[3];
    const int*   context_lens = (const int*)d_in[4];
    const int*   layout_crow  = (const int*)d_in[5];
    const int*   layout_col   = (const int*)d_in[6];
    const int    collen       = in_sizes[6] / H;
    float* out = (float*)d_out;
    float* ws  = (float*)d_ws;

    sparse_attn_split<<<B * H * NSPLIT, 256, 0, stream>>>(
        q, k_cache, v_cache, block_tables, context_lens,
        layout_crow, layout_col, collen, ws);
    sparse_attn_combine<<<B * H, 128, 0, stream>>>(ws, out);
}